// Round 2
// baseline (11811.876 us; speedup 1.0000x reference)
//
#include <hip/hip_runtime.h>
#include <hip/hip_bf16.h>
#include <math.h>

#define NHEADS 4
#define DMODEL 512
#define HQK 128
#define HV 256
#define CHK 64
#define BBATCH 8
#define SH 56
#define SWW 56
#define SEQN (SH*SWW)          // 3136
#define NTOK (BBATCH*SEQN)     // 25088
#define NCHUNK (SEQN/CHK)      // 49

__device__ __forceinline__ float silu_f(float v){ return v / (1.f + __expf(-v)); }

__device__ __forceinline__ float b2f(unsigned short u){
  union { unsigned int i; float f; } c; c.i = ((unsigned int)u) << 16; return c.f;
}
__device__ __forceinline__ unsigned short f2b(float f){
  union { float fv; unsigned int u; } c; c.fv = f;
  unsigned int r = c.u + 0x7FFFu + ((c.u >> 16) & 1u);   // RNE
  return (unsigned short)(r >> 16);
}

// ---------------- conv 3x3 depthwise + SiLU -> xs (bf16) ----------------
__global__ __launch_bounds__(256) void k_conv_silu(const float* __restrict__ x,
                                                   const float* __restrict__ cw,
                                                   unsigned short* __restrict__ xs){
  int gid = blockIdx.x*256 + threadIdx.x;     // NTOK*128 threads
  int c4  = (gid & 127) << 2;
  int tok = gid >> 7;
  int b = tok / SEQN, sp = tok % SEQN;
  int hh = sp / SWW, ww = sp % SWW;
  float a0=0.f,a1=0.f,a2=0.f,a3=0.f;
  #pragma unroll
  for (int dh=-1; dh<=1; ++dh){
    int h2 = hh+dh; if (h2<0||h2>=SH) continue;
    #pragma unroll
    for (int dw=-1; dw<=1; ++dw){
      int w2 = ww+dw; if (w2<0||w2>=SWW) continue;
      const float4 xv = *(const float4*)&x[((size_t)(b*SEQN + h2*SWW + w2))*DMODEL + c4];
      int tap = (dh+1)*3 + (dw+1);
      a0 += xv.x * cw[(c4+0)*9 + tap];
      a1 += xv.y * cw[(c4+1)*9 + tap];
      a2 += xv.z * cw[(c4+2)*9 + tap];
      a3 += xv.w * cw[(c4+3)*9 + tap];
    }
  }
  ushort4 o;
  o.x = f2b(silu_f(a0)); o.y = f2b(silu_f(a1)); o.z = f2b(silu_f(a2)); o.w = f2b(silu_f(a3));
  *(ushort4*)&xs[(size_t)tok*DMODEL + c4] = o;
}

// ------- GEMM: C[M,N] = act(A_bf16[M,K] * W_f32[N,K]^T + bias), C bf16 or f32 -------
// 128x128 tile, 8x8 micro-tile, BK=16
template<int ACT, int CBF>
__global__ __launch_bounds__(256) void k_gemm_bA(const unsigned short* __restrict__ A,
                                                 const float* __restrict__ W,
                                                 const float* __restrict__ bias,
                                                 void* __restrict__ Cv,
                                                 int M, int N, int K){
  __shared__ float sA[128*20];
  __shared__ float sW[128*20];
  const int tid = threadIdx.x;
  const int tx = tid & 15, ty = tid >> 4;
  const int m0 = blockIdx.y * 128, n0 = blockIdx.x * 128;
  const int arow = tid >> 1, ak8 = (tid & 1) << 3;
  float acc[8][8] = {};
  for (int kt = 0; kt < K; kt += 16){
    { // A tile 128x16 bf16 -> fp32 LDS
      uint4 ua = *(const uint4*)&A[(size_t)(m0+arow)*K + kt + ak8];
      float4 f0, f1;
      f0.x = b2f((unsigned short)ua.x); f0.y = b2f((unsigned short)(ua.x>>16));
      f0.z = b2f((unsigned short)ua.y); f0.w = b2f((unsigned short)(ua.y>>16));
      f1.x = b2f((unsigned short)ua.z); f1.y = b2f((unsigned short)(ua.z>>16));
      f1.z = b2f((unsigned short)ua.w); f1.w = b2f((unsigned short)(ua.w>>16));
      *(float4*)&sA[arow*20 + ak8]     = f0;
      *(float4*)&sA[arow*20 + ak8 + 4] = f1;
    }
    #pragma unroll
    for (int i=0;i<2;++i){
      int f = tid + i*256;
      int row = f >> 2, k4 = (f & 3) << 2;
      *(float4*)&sW[row*20 + k4] = *(const float4*)&W[(size_t)(n0+row)*K + kt + k4];
    }
    __syncthreads();
    #pragma unroll
    for (int kk=0;kk<16;++kk){
      float av[8], wv[8];
      #pragma unroll
      for (int r=0;r<8;++r){ int i = (r + 2*ty) & 7; av[i] = sA[(ty*8+i)*20 + kk]; }
      #pragma unroll
      for (int r=0;r<8;++r){ int j = (r + tx) & 7; wv[j] = sW[(tx*8+j)*20 + kk]; }
      #pragma unroll
      for (int i=0;i<8;++i)
        #pragma unroll
        for (int j=0;j<8;++j) acc[i][j] += av[i]*wv[j];
    }
    __syncthreads();
  }
  #pragma unroll
  for (int i=0;i<8;++i){
    size_t m = (size_t)(m0 + ty*8 + i);
    float vals[8];
    #pragma unroll
    for (int j=0;j<8;++j){
      int n = n0 + tx*8 + j;
      float v = acc[i][j];
      if (bias) v += bias[n];
      if (ACT==1) v = silu_f(v);
      vals[j] = v;
    }
    if (CBF){
      unsigned short* C = (unsigned short*)Cv;
      uint4 pk;
      pk.x = (unsigned)f2b(vals[0]) | ((unsigned)f2b(vals[1])<<16);
      pk.y = (unsigned)f2b(vals[2]) | ((unsigned)f2b(vals[3])<<16);
      pk.z = (unsigned)f2b(vals[4]) | ((unsigned)f2b(vals[5])<<16);
      pk.w = (unsigned)f2b(vals[6]) | ((unsigned)f2b(vals[7])<<16);
      *(uint4*)&C[m*(size_t)N + n0 + tx*8] = pk;
    } else {
      float* C = (float*)Cv;
      *(float4*)&C[m*(size_t)N + n0 + tx*8]     = make_float4(vals[0],vals[1],vals[2],vals[3]);
      *(float4*)&C[m*(size_t)N + n0 + tx*8 + 4] = make_float4(vals[4],vals[5],vals[6],vals[7]);
    }
  }
}

// ---------------- gk low-rank stage 1: gklo[M,16] = xs[M,512] @ w1[16,512]^T (fp32) --------
__global__ __launch_bounds__(256) void k_gklo(const unsigned short* __restrict__ xs,
                                              const float* __restrict__ w1,
                                              float* __restrict__ gklo){
  __shared__ float sW[16*516];
  const int tid = threadIdx.x;
  #pragma unroll
  for (int i=0;i<8;++i){
    int f = tid + i*256;
    int nr = f >> 7, k4 = (f & 127) << 2;
    *(float4*)&sW[nr*516 + k4] = *(const float4*)&w1[nr*512 + k4];
  }
  __syncthreads();
  int m = blockIdx.x*16 + (tid>>4);
  int nn = tid & 15;
  float acc = 0.f;
  for (int k=0;k<512;k+=8){
    uint4 xv = *(const uint4*)&xs[(size_t)m*512 + k];
    float xf[8];
    xf[0]=b2f((unsigned short)xv.x); xf[1]=b2f((unsigned short)(xv.x>>16));
    xf[2]=b2f((unsigned short)xv.y); xf[3]=b2f((unsigned short)(xv.y>>16));
    xf[4]=b2f((unsigned short)xv.z); xf[5]=b2f((unsigned short)(xv.z>>16));
    xf[6]=b2f((unsigned short)xv.w); xf[7]=b2f((unsigned short)(xv.w>>16));
    #pragma unroll
    for (int u=0;u<8;++u) acc += xf[u]*sW[nn*516 + k + u];
  }
  gklo[m*16+nn] = acc;
}

// ---------------- GLA chunked scan (both directions), gk computed on the fly ----------------
// grid = 256 blocks: (vq 0..3 | dir 0..1 | h 0..3 | b 0..7), 256 threads.
__global__ __launch_bounds__(256,1) void k_gla(const unsigned short* __restrict__ qkvb,
                                               const float* __restrict__ gklo,
                                               const float* __restrict__ w2,
                                               const float* __restrict__ b2a,
                                               unsigned short* __restrict__ og){
  __shared__ float sQeT[64*64];
  __shared__ float sKeT[64*64];
  __shared__ float sS[64*64];
  __shared__ float sV[64*64];

  const int tid = threadIdx.x;
  const int bx = blockIdx.x;
  const int vq = bx & 3, dir = (bx>>2)&1, hh = (bx>>3)&3, bb = bx>>5;
  const float scale = 0.08838834764831845f; // 128^-0.5

  const int wv  = tid >> 6;
  const int l   = tid & 63;
  const int cc  = l >> 2, seg = l & 3;
  const int dlb = (cc < 8) ? (8*wv + cc) : (8*wv + 24 + cc);  // build column (local d)
  const int t2  = tid >> 3;        // S-own rows t2, t2+32
  const int jg8 = tid & 7;         // S-own j cols jg8*8..+7
  const int ot  = tid >> 4;        // o/A rows ot*4..+3
  const int oj  = tid & 15;        // o cols / A s-cols oj*4..+3

  const int qcol = hh*HQK, kcol = 512 + hh*HQK, vcol = 1024 + hh*HV + vq*64;
  const int gcol = (dir ? 512 : 0) + hh*HQK;
  const size_t ogBase = ((size_t)((dir*BBATCH + bb)*NHEADS + hh)) * SEQN * HV;

  float Sreg[2][2][8];
  #pragma unroll
  for (int a=0;a<2;++a)
    #pragma unroll
    for (int b2_=0;b2_<2;++b2_)
      #pragma unroll
      for (int j=0;j<8;++j) Sreg[a][b2_][j] = 0.f;

  for (int c = 0; c < NCHUNK; ++c){
    float aA[4][4] = {}; float oI[4][4] = {};
    #pragma unroll
    for (int hf = 0; hf < 2; ++hf){
      // ---- P0: publish own S rows to sS; (hf==0) load v tile ----
      #pragma unroll
      for (int jj=0;jj<8;++jj){
        sS[t2*64 + jg8*8 + jj]      = Sreg[hf][0][jj];
        sS[(t2+32)*64 + jg8*8 + jj] = Sreg[hf][1][jj];
      }
      if (hf == 0){
        #pragma unroll
        for (int i=0;i<2;++i){
          int f = tid + i*256;
          int ss = f >> 3, j8 = (f & 7) << 3;
          int p = c*CHK + ss;
          int n = dir ? (SEQN-1-p) : p;
          size_t tok = (size_t)bb*SEQN + n;
          uint4 uv = *(const uint4*)&qkvb[tok*2048 + vcol + j8];
          float4 f0, f1;
          f0.x = b2f((unsigned short)uv.x); f0.y = b2f((unsigned short)(uv.x>>16));
          f0.z = b2f((unsigned short)uv.y); f0.w = b2f((unsigned short)(uv.y>>16));
          f1.x = b2f((unsigned short)uv.z); f1.y = b2f((unsigned short)(uv.z>>16));
          f1.z = b2f((unsigned short)uv.w); f1.w = b2f((unsigned short)(uv.w>>16));
          *(float4*)&sV[ss*64 + j8]     = f0;
          *(float4*)&sV[ss*64 + j8 + 4] = f1;
        }
      }
      __syncthreads();
      // ---- build: gk on the fly, cumsum gates, write qe^T, ke^T ----
      float eb0, eb1;
      {
        int d = hf*64 + dlb;
        int gc = gcol + d;
        float wrow[16];
        #pragma unroll
        for (int r=0;r<16;++r) wrow[r] = w2[gc*16 + r];
        float bb2 = b2a[gc];
        float bloc[16]; float run = 0.f;
        #pragma unroll
        for (int i=0;i<16;++i){
          int p = c*CHK + seg*16 + i;
          int n = dir ? (SEQN-1-p) : p;
          size_t tok = (size_t)bb*SEQN + n;
          const float* gl = &gklo[tok*16];
          float z = bb2;
          #pragma unroll
          for (int r=0;r<16;++r) z += gl[r]*wrow[r];
          float ls = (z >= 0.f) ? (-log1pf(__expf(-z))) : (z - log1pf(__expf(z)));
          run += ls * 0.0625f;
          bloc[i] = run;
        }
        float off = 0.f;
        float u1 = __shfl_up(run, 1u, 4); if (seg>=1) off += u1;
        float u2 = __shfl_up(run, 2u, 4); if (seg>=2) off += u2;
        float u3 = __shfl_up(run, 3u, 4); if (seg>=3) off += u3;
        float bfull = __shfl(off + run, 3, 4);
        float ebcol = __expf(bfull);
        #pragma unroll
        for (int i=0;i<16;++i){
          int p = c*CHK + seg*16 + i;
          int n = dir ? (SEQN-1-p) : p;
          size_t tok = (size_t)bb*SEQN + n;
          float bv = off + bloc[i];
          float qe = b2f(qkvb[tok*2048 + qcol + d]) * __expf(bv) * scale;
          float ke = b2f(qkvb[tok*2048 + kcol + d]) * __expf(-bv);
          sQeT[dlb*64 + seg*16 + i] = qe;
          sKeT[dlb*64 + seg*16 + i] = ke;
        }
        int srcb = ((tid>>3)&7) * 4;
        eb0 = __shfl(ebcol, srcb, 64);
        eb1 = __shfl(ebcol, srcb+32, 64);
      }
      __syncthreads();
      // ---- P3: A += qe ke^T ; o_inter += qe S_old ; S own-update ----
      #pragma unroll 4
      for (int dl=0; dl<64; ++dl){
        const float4 qv = *(const float4*)&sQeT[dl*64 + ot*4];
        const float4 kv = *(const float4*)&sKeT[dl*64 + oj*4];
        const float4 sv = *(const float4*)&sS[dl*64 + oj*4];
        float qp[4] = {qv.x,qv.y,qv.z,qv.w};
        float kp[4] = {kv.x,kv.y,kv.z,kv.w};
        float sp[4] = {sv.x,sv.y,sv.z,sv.w};
        #pragma unroll
        for (int i=0;i<4;++i)
          #pragma unroll
          for (int j=0;j<4;++j){
            aA[i][j] += qp[i]*kp[j];
            oI[i][j] += qp[i]*sp[j];
          }
      }
      float T0[8] = {}, T1[8] = {};
      #pragma unroll 2
      for (int s4=0; s4<64; s4+=4){
        float4 k0 = *(const float4*)&sKeT[t2*64 + s4];
        float4 k1 = *(const float4*)&sKeT[(t2+32)*64 + s4];
        float ku0[4] = {k0.x,k0.y,k0.z,k0.w};
        float ku1[4] = {k1.x,k1.y,k1.z,k1.w};
        #pragma unroll
        for (int u=0;u<4;++u){
          float4 va = *(const float4*)&sV[(s4+u)*64 + jg8*8];
          float4 vb = *(const float4*)&sV[(s4+u)*64 + jg8*8 + 4];
          float vv[8] = {va.x,va.y,va.z,va.w,vb.x,vb.y,vb.z,vb.w};
          #pragma unroll
          for (int jj=0;jj<8;++jj){
            T0[jj] += ku0[u]*vv[jj];
            T1[jj] += ku1[u]*vv[jj];
          }
        }
      }
      #pragma unroll
      for (int jj=0;jj<8;++jj){
        Sreg[hf][0][jj] = eb0*(Sreg[hf][0][jj] + T0[jj]);
        Sreg[hf][1][jj] = eb1*(Sreg[hf][1][jj] + T1[jj]);
      }
      __syncthreads();
    } // hf
    // ---- P4: masked A -> sA_T[s][t] (overlay sQeT) ----
    float* sAT = sQeT;
    #pragma unroll
    for (int i=0;i<4;++i){
      int t = ot*4+i;
      #pragma unroll
      for (int j=0;j<4;++j){
        int s = oj*4+j;
        sAT[s*64 + t] = (s <= t) ? aA[i][j] : 0.f;
      }
    }
    __syncthreads();
    // ---- P5: o_intra ; store o (bf16) ----
    #pragma unroll 4
    for (int s=0;s<64;++s){
      const float4 av = *(const float4*)&sAT[s*64 + ot*4];
      const float4 vv = *(const float4*)&sV[s*64 + oj*4];
      float ap[4] = {av.x,av.y,av.z,av.w};
      float vp[4] = {vv.x,vv.y,vv.z,vv.w};
      #pragma unroll
      for (int i=0;i<4;++i)
        #pragma unroll
        for (int j=0;j<4;++j) oI[i][j] += ap[i]*vp[j];
    }
    #pragma unroll
    for (int i=0;i<4;++i){
      int t = ot*4+i;
      int p = c*CHK + t;
      int n = dir ? (SEQN-1-p) : p;
      ushort4 ov;
      ov.x = f2b(oI[i][0]); ov.y = f2b(oI[i][1]); ov.z = f2b(oI[i][2]); ov.w = f2b(oI[i][3]);
      *(ushort4*)&og[ogBase + (size_t)n*HV + vq*64 + oj*4] = ov;
    }
    __syncthreads();
  } // chunks
}

// ---------------- rmsnorm(f)+rmsnorm(b), gate with silu(g) ----------------
__global__ __launch_bounds__(256) void k_gate(const unsigned short* __restrict__ og,
                                              const unsigned short* __restrict__ g,
                                              const float* __restrict__ gnw,
                                              const float* __restrict__ lnw,
                                              unsigned short* __restrict__ y){
  int tok = blockIdx.x;
  int bb = tok / SEQN, n = tok % SEQN;
  int hh = threadIdx.x >> 6, l = threadIdx.x & 63;
  int j4 = l << 2;
  size_t basef = ((size_t)((0*BBATCH+bb)*NHEADS+hh))*SEQN*HV + (size_t)n*HV + j4;
  size_t baseb = ((size_t)((1*BBATCH+bb)*NHEADS+hh))*SEQN*HV + (size_t)n*HV + j4;
  ushort4 ofu = *(const ushort4*)&og[basef];
  ushort4 obu = *(const ushort4*)&og[baseb];
  float of0=b2f(ofu.x), of1=b2f(ofu.y), of2=b2f(ofu.z), of3=b2f(ofu.w);
  float ob0=b2f(obu.x), ob1=b2f(obu.y), ob2=b2f(obu.z), ob3=b2f(obu.w);
  float ssf = of0*of0 + of1*of1 + of2*of2 + of3*of3;
  float ssb = ob0*ob0 + ob1*ob1 + ob2*ob2 + ob3*ob3;
  #pragma unroll
  for (int m=32;m>=1;m>>=1){ ssf += __shfl_xor(ssf,m,64); ssb += __shfl_xor(ssb,m,64); }
  float rf = rsqrtf(ssf*(1.f/HV) + 1e-5f);
  float rb = rsqrtf(ssb*(1.f/HV) + 1e-5f);
  float4 gn = *(const float4*)&gnw[j4];
  float4 ln = *(const float4*)&lnw[j4];
  ushort4 gvu = *(const ushort4*)&g[(size_t)tok*1024 + hh*HV + j4];  // silu already applied
  float g0=b2f(gvu.x), g1=b2f(gvu.y), g2=b2f(gvu.z), g3=b2f(gvu.w);
  ushort4 out;
  out.x = f2b(g0*(of0*rf*gn.x + ob0*rb*ln.x));
  out.y = f2b(g1*(of1*rf*gn.y + ob1*rb*ln.y));
  out.z = f2b(g2*(of2*rf*gn.z + ob2*rb*ln.z));
  out.w = f2b(g3*(of3*rf*gn.w + ob3*rb*ln.w));
  *(ushort4*)&y[(size_t)tok*1024 + hh*HV + j4] = out;
}

extern "C" void kernel_launch(void* const* d_in, const int* in_sizes, int n_in,
                              void* d_out, int out_size, void* d_ws, size_t ws_size,
                              hipStream_t stream){
  (void)in_sizes; (void)n_in; (void)out_size;
  const float* x    = (const float*)d_in[0];
  const float* cw   = (const float*)d_in[1];
  const float* qkvw = (const float*)d_in[2];
  const float* gkw1 = (const float*)d_in[3];
  const float* gkw2 = (const float*)d_in[4];
  const float* gkb2 = (const float*)d_in[5];
  const float* gw   = (const float*)d_in[6];
  const float* gb   = (const float*)d_in[7];
  const float* gnw  = (const float*)d_in[8];
  const float* lnw  = (const float*)d_in[9];
  const float* ow   = (const float*)d_in[10];

  // Workspace layout (bytes), total 232,816,640 (~233 MB):
  //   qkv bf16 [25088,2048]           @ 0          (102,760,448 B)  — later reused as y
  //   og  bf16 [2,8,4,3136,256]       @ 102760448  (102,760,448 B)
  //   xs  bf16 [25088,512]            @ 205520896  ( 25,690,112 B)
  //   gklo f32 [25088,16]             @ 231211008  (  1,605,632 B)
  // g (bf16 [25088,1024]) lives in d_out (exactly 51,380,224 B), consumed before final GEMM.
  if (ws_size < 232816640u) return;   // diagnostic guard: absmax would equal ref max (~2.43e-4)
  char* wsb = (char*)d_ws;
  unsigned short* qkv  = (unsigned short*)(wsb + 0);
  unsigned short* og   = (unsigned short*)(wsb + 102760448);
  unsigned short* xs   = (unsigned short*)(wsb + 205520896);
  float*          gklo = (float*)(wsb + 231211008);
  unsigned short* y    = qkv;                    // overlay: qkv dead after k_gla
  unsigned short* g    = (unsigned short*)d_out; // overlay: consumed by k_gate before final GEMM
  float*          outp = (float*)d_out;

  k_conv_silu<<<NTOK*128/256, 256, 0, stream>>>(x, cw, xs);
  k_gklo<<<NTOK/16, 256, 0, stream>>>(xs, gkw1, gklo);
  k_gemm_bA<0,1><<<dim3(16,196), 256, 0, stream>>>(xs, qkvw, nullptr, qkv, NTOK, 2048, 512);
  k_gemm_bA<1,1><<<dim3(8,196),  256, 0, stream>>>(xs, gw,   gb,      g,   NTOK, 1024, 512);
  k_gla<<<256, 256, 0, stream>>>(qkv, gklo, gkw2, gkb2, og);
  k_gate<<<NTOK, 256, 0, stream>>>(og, g, gnw, lnw, y);
  k_gemm_bA<0,0><<<dim3(4,196), 256, 0, stream>>>(y, ow, nullptr, outp, NTOK, 512, 1024);
}

// Round 3
// 2753.244 us; speedup vs baseline: 4.2902x; 4.2902x over previous
//
#include <hip/hip_runtime.h>
#include <hip/hip_bf16.h>
#include <math.h>

#define NHEADS 4
#define DMODEL 512
#define HQK 128
#define HV 256
#define CHK 64
#define BBATCH 8
#define SH 56
#define SWW 56
#define SEQN (SH*SWW)          // 3136
#define NTOK (BBATCH*SEQN)     // 25088
#define NCHUNK (SEQN/CHK)      // 49

typedef __bf16 bf16x8 __attribute__((ext_vector_type(8)));
typedef float  f32x4  __attribute__((ext_vector_type(4)));

__device__ __forceinline__ float silu_f(float v){ return v / (1.f + __expf(-v)); }

__device__ __forceinline__ float b2f(unsigned short u){
  union { unsigned int i; float f; } c; c.i = ((unsigned int)u) << 16; return c.f;
}
__device__ __forceinline__ unsigned short f2b(float f){
  union { float fv; unsigned int u; } c; c.fv = f;
  unsigned int r = c.u + 0x7FFFu + ((c.u >> 16) & 1u);   // RNE
  return (unsigned short)(r >> 16);
}

#define GLL16(gp, lp) __builtin_amdgcn_global_load_lds( \
    (const __attribute__((address_space(1))) unsigned int*)(gp), \
    (__attribute__((address_space(3))) unsigned int*)(lp), 16, 0, 0)

// ---------------- fp32 -> bf16 weight conversion ----------------
__global__ __launch_bounds__(256) void k_w2b(const float* __restrict__ w,
                                             unsigned short* __restrict__ o, int n){
  int i = (blockIdx.x*256 + threadIdx.x) << 2;
  if (i >= n) return;
  float4 v = *(const float4*)&w[i];
  ushort4 p;
  p.x = f2b(v.x); p.y = f2b(v.y); p.z = f2b(v.z); p.w = f2b(v.w);
  *(ushort4*)&o[i] = p;
}

// ---------------- conv 3x3 depthwise + SiLU -> xs (bf16) ----------------
__global__ __launch_bounds__(256) void k_conv_silu(const float* __restrict__ x,
                                                   const float* __restrict__ cw,
                                                   unsigned short* __restrict__ xs){
  int gid = blockIdx.x*256 + threadIdx.x;     // NTOK*128 threads
  int c4  = (gid & 127) << 2;
  int tok = gid >> 7;
  int b = tok / SEQN, sp = tok % SEQN;
  int hh = sp / SWW, ww = sp % SWW;
  float a0=0.f,a1=0.f,a2=0.f,a3=0.f;
  #pragma unroll
  for (int dh=-1; dh<=1; ++dh){
    int h2 = hh+dh; if (h2<0||h2>=SH) continue;
    #pragma unroll
    for (int dw=-1; dw<=1; ++dw){
      int w2 = ww+dw; if (w2<0||w2>=SWW) continue;
      const float4 xv = *(const float4*)&x[((size_t)(b*SEQN + h2*SWW + w2))*DMODEL + c4];
      int tap = (dh+1)*3 + (dw+1);
      a0 += xv.x * cw[(c4+0)*9 + tap];
      a1 += xv.y * cw[(c4+1)*9 + tap];
      a2 += xv.z * cw[(c4+2)*9 + tap];
      a3 += xv.w * cw[(c4+3)*9 + tap];
    }
  }
  ushort4 o;
  o.x = f2b(silu_f(a0)); o.y = f2b(silu_f(a1)); o.z = f2b(silu_f(a2)); o.w = f2b(silu_f(a3));
  *(ushort4*)&xs[(size_t)tok*DMODEL + c4] = o;
}

// ------- MFMA GEMM: C[M,N] = act(A_bf16[M,K] * W_bf16[N,K]^T + bias) -------
// m97 structure: 128x128 tile, 4 waves 2x2, BK=32, global_load_lds w=16,
// ds_read_b128 fragments, mfma_f32_16x16x32_bf16.
template<int ACT, int CBF>
__global__ __launch_bounds__(256) void k_gemm_mfma(const unsigned short* __restrict__ A,
                                                   const unsigned short* __restrict__ W,
                                                   const float* __restrict__ bias,
                                                   void* __restrict__ Cv,
                                                   int M, int N, int K){
  __shared__ unsigned short sA[128*32];
  __shared__ unsigned short sB[128*32];
  const int tid  = threadIdx.x;
  const int wave = tid >> 6, lane = tid & 63;
  const int lm = lane & 15, quad = lane >> 4;
  const int wm = wave & 1, wn = wave >> 1;
  const int m0 = blockIdx.y * 128, n0 = blockIdx.x * 128;

  // staging geometry: flat 16B chunk f covers row f>>2, k-chunk (f&3)*8
  const int r0 = tid >> 2,  c0 = (tid & 3) << 3;
  const int f1 = tid + 256;
  const int r1 = f1 >> 2,   c1 = (f1 & 3) << 3;

  f32x4 acc[4][4] = {};

  for (int kt = 0; kt < K; kt += 32){
    GLL16(&A[(size_t)(m0 + r0)*K + kt + c0], &sA[(size_t)tid*8]);
    GLL16(&A[(size_t)(m0 + r1)*K + kt + c1], &sA[(size_t)f1*8]);
    GLL16(&W[(size_t)(n0 + r0)*K + kt + c0], &sB[(size_t)tid*8]);
    GLL16(&W[(size_t)(n0 + r1)*K + kt + c1], &sB[(size_t)f1*8]);
    __syncthreads();
    bf16x8 af[4], bf[4];
    #pragma unroll
    for (int i=0;i<4;++i) af[i] = *(const bf16x8*)&sA[(wm*64 + i*16 + lm)*32 + quad*8];
    #pragma unroll
    for (int j=0;j<4;++j) bf[j] = *(const bf16x8*)&sB[(wn*64 + j*16 + lm)*32 + quad*8];
    #pragma unroll
    for (int i=0;i<4;++i)
      #pragma unroll
      for (int j=0;j<4;++j)
        acc[i][j] = __builtin_amdgcn_mfma_f32_16x16x32_bf16(af[i], bf[j], acc[i][j], 0, 0, 0);
    __syncthreads();
  }

  // epilogue: C/D layout col=lane&15, row=quad*4+reg
  #pragma unroll
  for (int i=0;i<4;++i){
    #pragma unroll
    for (int r=0;r<4;++r){
      size_t m = (size_t)(m0 + wm*64 + i*16 + quad*4 + r);
      #pragma unroll
      for (int j=0;j<4;++j){
        int n = n0 + wn*64 + j*16 + lm;
        float v = acc[i][j][r];
        if (bias) v += bias[n];
        if (ACT==1) v = silu_f(v);
        if (CBF) ((unsigned short*)Cv)[m*(size_t)N + n] = f2b(v);
        else     ((float*)Cv)[m*(size_t)N + n] = v;
      }
    }
  }
}

// ---------------- gk low-rank stage 1: gklo[M,16] = xs[M,512] @ w1[16,512]^T (fp32) --------
__global__ __launch_bounds__(256) void k_gklo(const unsigned short* __restrict__ xs,
                                              const float* __restrict__ w1,
                                              float* __restrict__ gklo){
  __shared__ float sW[16*516];
  const int tid = threadIdx.x;
  #pragma unroll
  for (int i=0;i<8;++i){
    int f = tid + i*256;
    int nr = f >> 7, k4 = (f & 127) << 2;
    *(float4*)&sW[nr*516 + k4] = *(const float4*)&w1[nr*512 + k4];
  }
  __syncthreads();
  int m = blockIdx.x*16 + (tid>>4);
  int nn = tid & 15;
  float acc = 0.f;
  for (int k=0;k<512;k+=8){
    uint4 xv = *(const uint4*)&xs[(size_t)m*512 + k];
    float xf[8];
    xf[0]=b2f((unsigned short)xv.x); xf[1]=b2f((unsigned short)(xv.x>>16));
    xf[2]=b2f((unsigned short)xv.y); xf[3]=b2f((unsigned short)(xv.y>>16));
    xf[4]=b2f((unsigned short)xv.z); xf[5]=b2f((unsigned short)(xv.z>>16));
    xf[6]=b2f((unsigned short)xv.w); xf[7]=b2f((unsigned short)(xv.w>>16));
    #pragma unroll
    for (int u=0;u<8;++u) acc += xf[u]*sW[nn*516 + k + u];
  }
  gklo[m*16+nn] = acc;
}

// ---------------- GLA chunked scan (both directions), gk computed on the fly ----------------
__global__ __launch_bounds__(256,1) void k_gla(const unsigned short* __restrict__ qkvb,
                                               const float* __restrict__ gklo,
                                               const float* __restrict__ w2,
                                               const float* __restrict__ b2a,
                                               unsigned short* __restrict__ og){
  __shared__ float sQeT[64*64];
  __shared__ float sKeT[64*64];
  __shared__ float sS[64*64];
  __shared__ float sV[64*64];

  const int tid = threadIdx.x;
  const int bx = blockIdx.x;
  const int vq = bx & 3, dir = (bx>>2)&1, hh = (bx>>3)&3, bb = bx>>5;
  const float scale = 0.08838834764831845f; // 128^-0.5

  const int wv  = tid >> 6;
  const int l   = tid & 63;
  const int cc  = l >> 2, seg = l & 3;
  const int dlb = (cc < 8) ? (8*wv + cc) : (8*wv + 24 + cc);  // build column (local d)
  const int t2  = tid >> 3;        // S-own rows t2, t2+32
  const int jg8 = tid & 7;         // S-own j cols jg8*8..+7
  const int ot  = tid >> 4;        // o/A rows ot*4..+3
  const int oj  = tid & 15;        // o cols / A s-cols oj*4..+3

  const int qcol = hh*HQK, kcol = 512 + hh*HQK, vcol = 1024 + hh*HV + vq*64;
  const int gcol = (dir ? 512 : 0) + hh*HQK;
  const size_t ogBase = ((size_t)((dir*BBATCH + bb)*NHEADS + hh)) * SEQN * HV;

  float Sreg[2][2][8];
  #pragma unroll
  for (int a=0;a<2;++a)
    #pragma unroll
    for (int b2_=0;b2_<2;++b2_)
      #pragma unroll
      for (int j=0;j<8;++j) Sreg[a][b2_][j] = 0.f;

  for (int c = 0; c < NCHUNK; ++c){
    float aA[4][4] = {}; float oI[4][4] = {};
    #pragma unroll
    for (int hf = 0; hf < 2; ++hf){
      #pragma unroll
      for (int jj=0;jj<8;++jj){
        sS[t2*64 + jg8*8 + jj]      = Sreg[hf][0][jj];
        sS[(t2+32)*64 + jg8*8 + jj] = Sreg[hf][1][jj];
      }
      if (hf == 0){
        #pragma unroll
        for (int i=0;i<2;++i){
          int f = tid + i*256;
          int ss = f >> 3, j8 = (f & 7) << 3;
          int p = c*CHK + ss;
          int n = dir ? (SEQN-1-p) : p;
          size_t tok = (size_t)bb*SEQN + n;
          uint4 uv = *(const uint4*)&qkvb[tok*2048 + vcol + j8];
          float4 f0, f1;
          f0.x = b2f((unsigned short)uv.x); f0.y = b2f((unsigned short)(uv.x>>16));
          f0.z = b2f((unsigned short)uv.y); f0.w = b2f((unsigned short)(uv.y>>16));
          f1.x = b2f((unsigned short)uv.z); f1.y = b2f((unsigned short)(uv.z>>16));
          f1.z = b2f((unsigned short)uv.w); f1.w = b2f((unsigned short)(uv.w>>16));
          *(float4*)&sV[ss*64 + j8]     = f0;
          *(float4*)&sV[ss*64 + j8 + 4] = f1;
        }
      }
      __syncthreads();
      float eb0, eb1;
      {
        int d = hf*64 + dlb;
        int gc = gcol + d;
        float wrow[16];
        #pragma unroll
        for (int r=0;r<16;++r) wrow[r] = w2[gc*16 + r];
        float bb2 = b2a[gc];
        float bloc[16]; float run = 0.f;
        #pragma unroll
        for (int i=0;i<16;++i){
          int p = c*CHK + seg*16 + i;
          int n = dir ? (SEQN-1-p) : p;
          size_t tok = (size_t)bb*SEQN + n;
          const float* gl = &gklo[tok*16];
          float z = bb2;
          #pragma unroll
          for (int r=0;r<16;++r) z += gl[r]*wrow[r];
          float ls = (z >= 0.f) ? (-log1pf(__expf(-z))) : (z - log1pf(__expf(z)));
          run += ls * 0.0625f;
          bloc[i] = run;
        }
        float off = 0.f;
        float u1 = __shfl_up(run, 1u, 4); if (seg>=1) off += u1;
        float u2 = __shfl_up(run, 2u, 4); if (seg>=2) off += u2;
        float u3 = __shfl_up(run, 3u, 4); if (seg>=3) off += u3;
        float bfull = __shfl(off + run, 3, 4);
        float ebcol = __expf(bfull);
        #pragma unroll
        for (int i=0;i<16;++i){
          int p = c*CHK + seg*16 + i;
          int n = dir ? (SEQN-1-p) : p;
          size_t tok = (size_t)bb*SEQN + n;
          float bv = off + bloc[i];
          float qe = b2f(qkvb[tok*2048 + qcol + d]) * __expf(bv) * scale;
          float ke = b2f(qkvb[tok*2048 + kcol + d]) * __expf(-bv);
          sQeT[dlb*64 + seg*16 + i] = qe;
          sKeT[dlb*64 + seg*16 + i] = ke;
        }
        int srcb = ((tid>>3)&7) * 4;
        eb0 = __shfl(ebcol, srcb, 64);
        eb1 = __shfl(ebcol, srcb+32, 64);
      }
      __syncthreads();
      #pragma unroll 4
      for (int dl=0; dl<64; ++dl){
        const float4 qv = *(const float4*)&sQeT[dl*64 + ot*4];
        const float4 kv = *(const float4*)&sKeT[dl*64 + oj*4];
        const float4 sv = *(const float4*)&sS[dl*64 + oj*4];
        float qp[4] = {qv.x,qv.y,qv.z,qv.w};
        float kp[4] = {kv.x,kv.y,kv.z,kv.w};
        float sp[4] = {sv.x,sv.y,sv.z,sv.w};
        #pragma unroll
        for (int i=0;i<4;++i)
          #pragma unroll
          for (int j=0;j<4;++j){
            aA[i][j] += qp[i]*kp[j];
            oI[i][j] += qp[i]*sp[j];
          }
      }
      float T0[8] = {}, T1[8] = {};
      #pragma unroll 2
      for (int s4=0; s4<64; s4+=4){
        float4 k0 = *(const float4*)&sKeT[t2*64 + s4];
        float4 k1 = *(const float4*)&sKeT[(t2+32)*64 + s4];
        float ku0[4] = {k0.x,k0.y,k0.z,k0.w};
        float ku1[4] = {k1.x,k1.y,k1.z,k1.w};
        #pragma unroll
        for (int u=0;u<4;++u){
          float4 va = *(const float4*)&sV[(s4+u)*64 + jg8*8];
          float4 vb = *(const float4*)&sV[(s4+u)*64 + jg8*8 + 4];
          float vv[8] = {va.x,va.y,va.z,va.w,vb.x,vb.y,vb.z,vb.w};
          #pragma unroll
          for (int jj=0;jj<8;++jj){
            T0[jj] += ku0[u]*vv[jj];
            T1[jj] += ku1[u]*vv[jj];
          }
        }
      }
      #pragma unroll
      for (int jj=0;jj<8;++jj){
        Sreg[hf][0][jj] = eb0*(Sreg[hf][0][jj] + T0[jj]);
        Sreg[hf][1][jj] = eb1*(Sreg[hf][1][jj] + T1[jj]);
      }
      __syncthreads();
    } // hf
    float* sAT = sQeT;
    #pragma unroll
    for (int i=0;i<4;++i){
      int t = ot*4+i;
      #pragma unroll
      for (int j=0;j<4;++j){
        int s = oj*4+j;
        sAT[s*64 + t] = (s <= t) ? aA[i][j] : 0.f;
      }
    }
    __syncthreads();
    #pragma unroll 4
    for (int s=0;s<64;++s){
      const float4 av = *(const float4*)&sAT[s*64 + ot*4];
      const float4 vv = *(const float4*)&sV[s*64 + oj*4];
      float ap[4] = {av.x,av.y,av.z,av.w};
      float vp[4] = {vv.x,vv.y,vv.z,vv.w};
      #pragma unroll
      for (int i=0;i<4;++i)
        #pragma unroll
        for (int j=0;j<4;++j) oI[i][j] += ap[i]*vp[j];
    }
    #pragma unroll
    for (int i=0;i<4;++i){
      int t = ot*4+i;
      int p = c*CHK + t;
      int n = dir ? (SEQN-1-p) : p;
      ushort4 ov;
      ov.x = f2b(oI[i][0]); ov.y = f2b(oI[i][1]); ov.z = f2b(oI[i][2]); ov.w = f2b(oI[i][3]);
      *(ushort4*)&og[ogBase + (size_t)n*HV + vq*64 + oj*4] = ov;
    }
    __syncthreads();
  } // chunks
}

// ---------------- rmsnorm(f)+rmsnorm(b), gate with silu(g) ----------------
__global__ __launch_bounds__(256) void k_gate(const unsigned short* __restrict__ og,
                                              const unsigned short* __restrict__ g,
                                              const float* __restrict__ gnw,
                                              const float* __restrict__ lnw,
                                              unsigned short* __restrict__ y){
  int tok = blockIdx.x;
  int bb = tok / SEQN, n = tok % SEQN;
  int hh = threadIdx.x >> 6, l = threadIdx.x & 63;
  int j4 = l << 2;
  size_t basef = ((size_t)((0*BBATCH+bb)*NHEADS+hh))*SEQN*HV + (size_t)n*HV + j4;
  size_t baseb = ((size_t)((1*BBATCH+bb)*NHEADS+hh))*SEQN*HV + (size_t)n*HV + j4;
  ushort4 ofu = *(const ushort4*)&og[basef];
  ushort4 obu = *(const ushort4*)&og[baseb];
  float of0=b2f(ofu.x), of1=b2f(ofu.y), of2=b2f(ofu.z), of3=b2f(ofu.w);
  float ob0=b2f(obu.x), ob1=b2f(obu.y), ob2=b2f(obu.z), ob3=b2f(obu.w);
  float ssf = of0*of0 + of1*of1 + of2*of2 + of3*of3;
  float ssb = ob0*ob0 + ob1*ob1 + ob2*ob2 + ob3*ob3;
  #pragma unroll
  for (int m=32;m>=1;m>>=1){ ssf += __shfl_xor(ssf,m,64); ssb += __shfl_xor(ssb,m,64); }
  float rf = rsqrtf(ssf*(1.f/HV) + 1e-5f);
  float rb = rsqrtf(ssb*(1.f/HV) + 1e-5f);
  float4 gn = *(const float4*)&gnw[j4];
  float4 ln = *(const float4*)&lnw[j4];
  ushort4 gvu = *(const ushort4*)&g[(size_t)tok*1024 + hh*HV + j4];  // silu already applied
  float g0=b2f(gvu.x), g1=b2f(gvu.y), g2=b2f(gvu.z), g3=b2f(gvu.w);
  ushort4 out;
  out.x = f2b(g0*(of0*rf*gn.x + ob0*rb*ln.x));
  out.y = f2b(g1*(of1*rf*gn.y + ob1*rb*ln.y));
  out.z = f2b(g2*(of2*rf*gn.z + ob2*rb*ln.z));
  out.w = f2b(g3*(of3*rf*gn.w + ob3*rb*ln.w));
  *(ushort4*)&y[(size_t)tok*1024 + hh*HV + j4] = out;
}

extern "C" void kernel_launch(void* const* d_in, const int* in_sizes, int n_in,
                              void* d_out, int out_size, void* d_ws, size_t ws_size,
                              hipStream_t stream){
  (void)in_sizes; (void)n_in; (void)out_size;
  const float* x    = (const float*)d_in[0];
  const float* cw   = (const float*)d_in[1];
  const float* qkvw = (const float*)d_in[2];
  const float* gkw1 = (const float*)d_in[3];
  const float* gkw2 = (const float*)d_in[4];
  const float* gkb2 = (const float*)d_in[5];
  const float* gw   = (const float*)d_in[6];
  const float* gb   = (const float*)d_in[7];
  const float* gnw  = (const float*)d_in[8];
  const float* lnw  = (const float*)d_in[9];
  const float* ow   = (const float*)d_in[10];

  // Workspace layout (bytes), total 232,816,640 (~233 MB):
  //   qkv bf16 [25088,2048]           @ 0          (102,760,448 B)  — later reused as y
  //   og  bf16 [2,8,4,3136,256]       @ 102760448  (102,760,448 B)
  //       head of og region doubles as bf16 weight staging:
  //       qkvw_b (2 MB) + gw_b (1 MB) dead before k_gla writes og;
  //       ow_b (1 MB) converted after k_gate when og is dead.
  //   xs  bf16 [25088,512]            @ 205520896  ( 25,690,112 B)
  //   gklo f32 [25088,16]             @ 231211008  (  1,605,632 B)
  // g (bf16 [25088,1024]) lives in d_out, consumed before final GEMM.
  if (ws_size < 232816640u) return;
  char* wsb = (char*)d_ws;
  unsigned short* qkv  = (unsigned short*)(wsb + 0);
  unsigned short* og   = (unsigned short*)(wsb + 102760448);
  unsigned short* xs   = (unsigned short*)(wsb + 205520896);
  float*          gklo = (float*)(wsb + 231211008);
  unsigned short* wqb  = og;                         // 2048*512 bf16 (2 MB)
  unsigned short* wgb  = og + 1048576;               // 1024*512 bf16 (1 MB)
  unsigned short* wob  = og;                         // 512*1024 bf16 (1 MB), after k_gate
  unsigned short* y    = qkv;                        // overlay: qkv dead after k_gla
  unsigned short* g    = (unsigned short*)d_out;     // overlay: consumed by k_gate
  float*          outp = (float*)d_out;

  k_conv_silu<<<NTOK*128/256, 256, 0, stream>>>(x, cw, xs);
  k_w2b<<<1024, 256, 0, stream>>>(qkvw, wqb, 2048*512);
  k_w2b<<<512,  256, 0, stream>>>(gw,   wgb, 1024*512);
  k_gklo<<<NTOK/16, 256, 0, stream>>>(xs, gkw1, gklo);
  k_gemm_mfma<0,1><<<dim3(16,196), 256, 0, stream>>>(xs, wqb, nullptr, qkv, NTOK, 2048, 512);
  k_gemm_mfma<1,1><<<dim3(8,196),  256, 0, stream>>>(xs, wgb, gb,      g,   NTOK, 1024, 512);
  k_gla<<<256, 256, 0, stream>>>(qkv, gklo, gkw2, gkb2, og);
  k_gate<<<NTOK, 256, 0, stream>>>(og, g, gnw, lnw, y);
  k_w2b<<<512, 256, 0, stream>>>(ow, wob, 512*1024);
  k_gemm_mfma<0,0><<<dim3(4,196), 256, 0, stream>>>(y, wob, nullptr, outp, NTOK, 512, 1024);
}

// Round 5
// 2595.991 us; speedup vs baseline: 4.5500x; 1.0606x over previous
//
#include <hip/hip_runtime.h>
#include <hip/hip_bf16.h>
#include <math.h>

#define NHEADS 4
#define DMODEL 512
#define HQK 128
#define HV 256
#define CHK 64
#define BBATCH 8
#define SH 56
#define SWW 56
#define SEQN (SH*SWW)          // 3136
#define NTOK (BBATCH*SEQN)     // 25088
#define CH2 32
#define NC2 (SEQN/CH2)         // 98

typedef __bf16 bf16x8 __attribute__((ext_vector_type(8)));
typedef float  f32x4  __attribute__((ext_vector_type(4)));

__device__ __forceinline__ float silu_f(float v){ return v / (1.f + __expf(-v)); }

__device__ __forceinline__ float b2f(unsigned short u){
  union { unsigned int i; float f; } c; c.i = ((unsigned int)u) << 16; return c.f;
}
__device__ __forceinline__ unsigned short f2b(float f){
  union { float fv; unsigned int u; } c; c.fv = f;
  unsigned int r = c.u + 0x7FFFu + ((c.u >> 16) & 1u);   // RNE
  return (unsigned short)(r >> 16);
}

#define GLL16(gp, lp) __builtin_amdgcn_global_load_lds( \
    (const __attribute__((address_space(1))) unsigned int*)(gp), \
    (__attribute__((address_space(3))) unsigned int*)(lp), 16, 0, 0)

// ---------------- fp32 -> bf16 weight conversion ----------------
__global__ __launch_bounds__(256) void k_w2b(const float* __restrict__ w,
                                             unsigned short* __restrict__ o, int n){
  int i = (blockIdx.x*256 + threadIdx.x) << 2;
  if (i >= n) return;
  float4 v = *(const float4*)&w[i];
  ushort4 p;
  p.x = f2b(v.x); p.y = f2b(v.y); p.z = f2b(v.z); p.w = f2b(v.w);
  *(ushort4*)&o[i] = p;
}

// ---------------- conv 3x3 depthwise + SiLU -> xs (bf16) ----------------
__global__ __launch_bounds__(256) void k_conv_silu(const float* __restrict__ x,
                                                   const float* __restrict__ cw,
                                                   unsigned short* __restrict__ xs){
  int gid = blockIdx.x*256 + threadIdx.x;     // NTOK*128 threads
  int c4  = (gid & 127) << 2;
  int tok = gid >> 7;
  int b = tok / SEQN, sp = tok % SEQN;
  int hh = sp / SWW, ww = sp % SWW;
  float a0=0.f,a1=0.f,a2=0.f,a3=0.f;
  #pragma unroll
  for (int dh=-1; dh<=1; ++dh){
    int h2 = hh+dh; if (h2<0||h2>=SH) continue;
    #pragma unroll
    for (int dw=-1; dw<=1; ++dw){
      int w2 = ww+dw; if (w2<0||w2>=SWW) continue;
      const float4 xv = *(const float4*)&x[((size_t)(b*SEQN + h2*SWW + w2))*DMODEL + c4];
      int tap = (dh+1)*3 + (dw+1);
      a0 += xv.x * cw[(c4+0)*9 + tap];
      a1 += xv.y * cw[(c4+1)*9 + tap];
      a2 += xv.z * cw[(c4+2)*9 + tap];
      a3 += xv.w * cw[(c4+3)*9 + tap];
    }
  }
  ushort4 o;
  o.x = f2b(silu_f(a0)); o.y = f2b(silu_f(a1)); o.z = f2b(silu_f(a2)); o.w = f2b(silu_f(a3));
  *(ushort4*)&xs[(size_t)tok*DMODEL + c4] = o;
}

// ------- MFMA GEMM: C[M,N] = act(A_bf16[M,K] * W_bf16[N,K]^T + bias) -------
template<int ACT, int CBF>
__global__ __launch_bounds__(256) void k_gemm_mfma(const unsigned short* __restrict__ A,
                                                   const unsigned short* __restrict__ W,
                                                   const float* __restrict__ bias,
                                                   void* __restrict__ Cv,
                                                   int M, int N, int K){
  __shared__ unsigned short sA[128*32];
  __shared__ unsigned short sB[128*32];
  const int tid  = threadIdx.x;
  const int wave = tid >> 6, lane = tid & 63;
  const int lm = lane & 15, quad = lane >> 4;
  const int wm = wave & 1, wn = wave >> 1;
  const int m0 = blockIdx.y * 128, n0 = blockIdx.x * 128;

  const int r0 = tid >> 2,  c0 = (tid & 3) << 3;
  const int f1 = tid + 256;
  const int r1 = f1 >> 2,   c1 = (f1 & 3) << 3;

  f32x4 acc[4][4] = {};

  for (int kt = 0; kt < K; kt += 32){
    GLL16(&A[(size_t)(m0 + r0)*K + kt + c0], &sA[(size_t)tid*8]);
    GLL16(&A[(size_t)(m0 + r1)*K + kt + c1], &sA[(size_t)f1*8]);
    GLL16(&W[(size_t)(n0 + r0)*K + kt + c0], &sB[(size_t)tid*8]);
    GLL16(&W[(size_t)(n0 + r1)*K + kt + c1], &sB[(size_t)f1*8]);
    __syncthreads();
    bf16x8 af[4], bf[4];
    #pragma unroll
    for (int i=0;i<4;++i) af[i] = *(const bf16x8*)&sA[(wm*64 + i*16 + lm)*32 + quad*8];
    #pragma unroll
    for (int j=0;j<4;++j) bf[j] = *(const bf16x8*)&sB[(wn*64 + j*16 + lm)*32 + quad*8];
    #pragma unroll
    for (int i=0;i<4;++i)
      #pragma unroll
      for (int j=0;j<4;++j)
        acc[i][j] = __builtin_amdgcn_mfma_f32_16x16x32_bf16(af[i], bf[j], acc[i][j], 0, 0, 0);
    __syncthreads();
  }

  #pragma unroll
  for (int i=0;i<4;++i){
    #pragma unroll
    for (int r=0;r<4;++r){
      size_t m = (size_t)(m0 + wm*64 + i*16 + quad*4 + r);
      #pragma unroll
      for (int j=0;j<4;++j){
        int n = n0 + wn*64 + j*16 + lm;
        float v = acc[i][j][r];
        if (bias) v += bias[n];
        if (ACT==1) v = silu_f(v);
        if (CBF) ((unsigned short*)Cv)[m*(size_t)N + n] = f2b(v);
        else     ((float*)Cv)[m*(size_t)N + n] = v;
      }
    }
  }
}

// ---------------- gk low-rank stage 1: gklo[M,16] = xs[M,512] @ w1[16,512]^T (fp32) --------
__global__ __launch_bounds__(256) void k_gklo(const unsigned short* __restrict__ xs,
                                              const float* __restrict__ w1,
                                              float* __restrict__ gklo){
  __shared__ float sW[16*516];
  const int tid = threadIdx.x;
  #pragma unroll
  for (int i=0;i<8;++i){
    int f = tid + i*256;
    int nr = f >> 7, k4 = (f & 127) << 2;
    *(float4*)&sW[nr*516 + k4] = *(const float4*)&w1[nr*512 + k4];
  }
  __syncthreads();
  int m = blockIdx.x*16 + (tid>>4);
  int nn = tid & 15;
  float acc = 0.f;
  for (int k=0;k<512;k+=8){
    uint4 xv = *(const uint4*)&xs[(size_t)m*512 + k];
    float xf[8];
    xf[0]=b2f((unsigned short)xv.x); xf[1]=b2f((unsigned short)(xv.x>>16));
    xf[2]=b2f((unsigned short)xv.y); xf[3]=b2f((unsigned short)(xv.y>>16));
    xf[4]=b2f((unsigned short)xv.z); xf[5]=b2f((unsigned short)(xv.z>>16));
    xf[6]=b2f((unsigned short)xv.w); xf[7]=b2f((unsigned short)(xv.w>>16));
    #pragma unroll
    for (int u=0;u<8;++u) acc += xf[u]*sW[nn*516 + k + u];
  }
  gklo[m*16+nn] = acc;
}

// ---------------- GLA chunked scan, full-MFMA version, CHUNK=32 ----------------
// grid = 256 blocks: (vq 0..3 | dir 0..1 | h 0..3 | b 0..7), 256 threads (4 waves).
// All tile products on mfma_f32_16x16x32_bf16; S master fp32 in accumulators,
// bf16 LDS mirror ST[v][d] feeds the o_inter MFMA. Outputs computed transposed
// (oT[v][t]) so every fragment is a contiguous ds_read_b128.
__global__ __launch_bounds__(256,1) void k_gla2(const unsigned short* __restrict__ qkvb,
                                                const float* __restrict__ gklo,
                                                const float* __restrict__ w2,
                                                const float* __restrict__ b2a,
                                                unsigned short* __restrict__ og){
  __shared__ __align__(16) unsigned short sQe[32*136];   // [t][d] stride 136 (272B rows)
  __shared__ __align__(16) unsigned short sKe[32*136];   // [t][d]
  __shared__ __align__(16) unsigned short sKeT[128*40];  // [d][t] stride 40 (80B rows)
  __shared__ __align__(16) unsigned short sVT[64*40];    // [v][t]
  __shared__ __align__(16) unsigned short sST[64*136];   // [v][d]  (bf16 mirror of S)
  __shared__ __align__(16) unsigned short sP[32*40];     // [t][s]
  __shared__ __align__(16) unsigned short sO[32*72];     // [t][v] staging for store
  __shared__ float sEbF[128];
  __shared__ float sSeg[128];
  __shared__ float sGlo[32*18];

  const int tid = threadIdx.x;
  const int bx = blockIdx.x;
  const int vq = bx & 3, dir = (bx>>2)&1, hh = (bx>>3)&3, bb = bx>>5;
  const float scale = 0.08838834764831845f; // 128^-0.5

  const int w = tid >> 6, lane = tid & 63;
  const int quad = lane >> 4, lm = lane & 15;
  const int d = tid & 127, seg = tid >> 7;          // build mapping
  const int mt = w >> 1, nt = w & 1;                // op1 tile

  const int qcol = hh*HQK, kcol = 512 + hh*HQK, vcol = 1024 + hh*HV + vq*64;
  const int gc = (dir ? 512 : 0) + hh*HQK + d;
  const size_t ogBase = ((size_t)((dir*BBATCH + bb)*NHEADS + hh)) * SEQN * HV;

  float wrow[16];
  #pragma unroll
  for (int r=0;r<16;++r) wrow[r] = w2[gc*16 + r];
  const float bb2 = b2a[gc];

  f32x4 Sreg[8];
  #pragma unroll
  for (int i=0;i<8;++i){
    #pragma unroll
    for (int r=0;r<4;++r) Sreg[i][r] = 0.f;
  }
  for (int i = tid; i < 64*136; i += 256) sST[i] = 0;
  __syncthreads();

  for (int c = 0; c < NC2; ++c){
    // ---- stage gklo chunk + V tile (transposed) ----
    {
      int i = tid >> 3, rr = (tid & 7) << 1;
      int p = c*CH2 + i; int n = dir ? (SEQN-1-p) : p;
      size_t tok = (size_t)bb*SEQN + n;
      sGlo[i*18 + rr]     = gklo[tok*16 + rr];
      sGlo[i*18 + rr + 1] = gklo[tok*16 + rr + 1];
    }
    {
      int tl = tid & 31, vg = tid >> 5;
      int p = c*CH2 + tl; int n = dir ? (SEQN-1-p) : p;
      size_t tok = (size_t)bb*SEQN + n;
      uint4 uv = *(const uint4*)&qkvb[tok*2048 + vcol + vg*8];
      unsigned short su[8] = { (unsigned short)uv.x, (unsigned short)(uv.x>>16),
                               (unsigned short)uv.y, (unsigned short)(uv.y>>16),
                               (unsigned short)uv.z, (unsigned short)(uv.z>>16),
                               (unsigned short)uv.w, (unsigned short)(uv.w>>16) };
      #pragma unroll
      for (int u=0;u<8;++u) sVT[(vg*8+u)*40 + tl] = su[u];
    }
    __syncthreads();                                   // sGlo staged
    // ---- gates: z = gklo . w2row + b2; logsigmoid/16; prefix over 32 ----
    float bloc[16]; float run = 0.f;
    #pragma unroll
    for (int i=0;i<16;++i){
      const float* gl = &sGlo[(seg*16+i)*18];
      float z = bb2;
      #pragma unroll
      for (int r=0;r<4;++r){
        float4 gv = *(const float4*)&gl[r*4];
        z += gv.x*wrow[r*4] + gv.y*wrow[r*4+1] + gv.z*wrow[r*4+2] + gv.w*wrow[r*4+3];
      }
      float e = __expf(-fabsf(z));
      float l = __logf(1.f + e);
      float ls = fminf(z, 0.f) - l;                    // logsigmoid(z)
      run += ls * 0.0625f;
      bloc[i] = run;
    }
    if (seg == 0) sSeg[d] = run;
    __syncthreads();
    float off = seg ? sSeg[d] : 0.f;
    if (seg == 1) sEbF[d] = __expf(off + run);         // exp(btot) per d
    // ---- qe/ke build ----
    #pragma unroll
    for (int i=0;i<16;++i){
      int t = seg*16 + i;
      int p = c*CH2 + t; int n = dir ? (SEQN-1-p) : p;
      size_t tok = (size_t)bb*SEQN + n;
      float bv = off + bloc[i];
      float qe = b2f(qkvb[tok*2048 + qcol + d]) * __expf(bv) * scale;
      float ke = b2f(qkvb[tok*2048 + kcol + d]) * __expf(-bv);
      unsigned short keb = f2b(ke);
      sQe[t*136 + d] = f2b(qe);
      sKe[t*136 + d] = keb;
      sKeT[d*40 + t] = keb;
    }
    __syncthreads();                                   // tiles + eb ready
    // ---- op1: A[t][s] = Qe.Ke^T ; op2T: oT[v][t] += ST.Qe^T ----
    bf16x8 qf[2][4];
    #pragma unroll
    for (int tt=0; tt<2; ++tt){
      #pragma unroll
      for (int ks=0; ks<4; ++ks)
        qf[tt][ks] = *(const bf16x8*)&sQe[(tt*16+lm)*136 + ks*32 + quad*8];
    }
    f32x4 a1;
    #pragma unroll
    for (int r=0;r<4;++r) a1[r] = 0.f;
    #pragma unroll
    for (int ks=0; ks<4; ++ks){
      bf16x8 kfr = *(const bf16x8*)&sKe[(nt*16+lm)*136 + ks*32 + quad*8];
      a1 = __builtin_amdgcn_mfma_f32_16x16x32_bf16(qf[mt][ks], kfr, a1, 0, 0, 0);
    }
    f32x4 ot[2];
    #pragma unroll
    for (int tt=0; tt<2; ++tt){
      #pragma unroll
      for (int r=0;r<4;++r) ot[tt][r] = 0.f;
    }
    #pragma unroll
    for (int ks=0; ks<4; ++ks){
      bf16x8 stf = *(const bf16x8*)&sST[(w*16+lm)*136 + ks*32 + quad*8];
      #pragma unroll
      for (int tt=0; tt<2; ++tt)
        ot[tt] = __builtin_amdgcn_mfma_f32_16x16x32_bf16(stf, qf[tt][ks], ot[tt], 0, 0, 0);
    }
    // ---- P = mask(A) -> sP ----
    #pragma unroll
    for (int r=0;r<4;++r){
      int t = mt*16 + quad*4 + r, s = nt*16 + lm;
      sP[t*40 + s] = f2b((s <= t) ? a1[r] : 0.f);
    }
    __syncthreads();                                   // sP ready, sST reads done
    // ---- op3T: S'[v][d] = eb * (S + VT.KeT^T) ; op4T: oT += VT.P^T ----
    bf16x8 vta = *(const bf16x8*)&sVT[(w*16+lm)*40 + quad*8];
    #pragma unroll
    for (int dt=0; dt<8; ++dt){
      bf16x8 kt = *(const bf16x8*)&sKeT[(dt*16+lm)*40 + quad*8];
      Sreg[dt] = __builtin_amdgcn_mfma_f32_16x16x32_bf16(vta, kt, Sreg[dt], 0, 0, 0);
      float eb = sEbF[dt*16 + lm];
      #pragma unroll
      for (int r=0;r<4;++r){
        float sv = Sreg[dt][r] * eb;
        Sreg[dt][r] = sv;
        sST[(w*16 + quad*4 + r)*136 + dt*16 + lm] = f2b(sv);
      }
    }
    #pragma unroll
    for (int tt=0; tt<2; ++tt){
      bf16x8 pf = *(const bf16x8*)&sP[(tt*16+lm)*40 + quad*8];
      ot[tt] = __builtin_amdgcn_mfma_f32_16x16x32_bf16(vta, pf, ot[tt], 0, 0, 0);
      #pragma unroll
      for (int r=0;r<4;++r)
        sO[(tt*16+lm)*72 + w*16 + quad*4 + r] = f2b(ot[tt][r]);
    }
    __syncthreads();                                   // sO ready
    // ---- coalesced o store ----
    {
      int t = tid >> 3, v8 = (tid & 7) << 3;
      int p = c*CH2 + t; int n = dir ? (SEQN-1-p) : p;
      uint4 pk = *(const uint4*)&sO[t*72 + v8];
      *(uint4*)&og[ogBase + (size_t)n*HV + vq*64 + v8] = pk;
    }
  } // chunks
}

// ---------------- rmsnorm(f)+rmsnorm(b), gate with silu(g) ----------------
__global__ __launch_bounds__(256) void k_gate(const unsigned short* __restrict__ og,
                                              const unsigned short* __restrict__ g,
                                              const float* __restrict__ gnw,
                                              const float* __restrict__ lnw,
                                              unsigned short* __restrict__ y){
  int tok = blockIdx.x;
  int bb = tok / SEQN, n = tok % SEQN;
  int hh = threadIdx.x >> 6, l = threadIdx.x & 63;
  int j4 = l << 2;
  size_t basef = ((size_t)((0*BBATCH+bb)*NHEADS+hh))*SEQN*HV + (size_t)n*HV + j4;
  size_t baseb = ((size_t)((1*BBATCH+bb)*NHEADS+hh))*SEQN*HV + (size_t)n*HV + j4;
  ushort4 ofu = *(const ushort4*)&og[basef];
  ushort4 obu = *(const ushort4*)&og[baseb];
  float of0=b2f(ofu.x), of1=b2f(ofu.y), of2=b2f(ofu.z), of3=b2f(ofu.w);
  float ob0=b2f(obu.x), ob1=b2f(obu.y), ob2=b2f(obu.z), ob3=b2f(obu.w);
  float ssf = of0*of0 + of1*of1 + of2*of2 + of3*of3;
  float ssb = ob0*ob0 + ob1*ob1 + ob2*ob2 + ob3*ob3;
  #pragma unroll
  for (int m=32;m>=1;m>>=1){ ssf += __shfl_xor(ssf,m,64); ssb += __shfl_xor(ssb,m,64); }
  float rf = rsqrtf(ssf*(1.f/HV) + 1e-5f);
  float rb = rsqrtf(ssb*(1.f/HV) + 1e-5f);
  float4 gn = *(const float4*)&gnw[j4];
  float4 ln = *(const float4*)&lnw[j4];
  ushort4 gvu = *(const ushort4*)&g[(size_t)tok*1024 + hh*HV + j4];  // silu already applied
  float g0=b2f(gvu.x), g1=b2f(gvu.y), g2=b2f(gvu.z), g3=b2f(gvu.w);
  ushort4 out;
  out.x = f2b(g0*(of0*rf*gn.x + ob0*rb*ln.x));
  out.y = f2b(g1*(of1*rf*gn.y + ob1*rb*ln.y));
  out.z = f2b(g2*(of2*rf*gn.z + ob2*rb*ln.z));
  out.w = f2b(g3*(of3*rf*gn.w + ob3*rb*ln.w));
  *(ushort4*)&y[(size_t)tok*1024 + hh*HV + j4] = out;
}

extern "C" void kernel_launch(void* const* d_in, const int* in_sizes, int n_in,
                              void* d_out, int out_size, void* d_ws, size_t ws_size,
                              hipStream_t stream){
  (void)in_sizes; (void)n_in; (void)out_size;
  const float* x    = (const float*)d_in[0];
  const float* cw   = (const float*)d_in[1];
  const float* qkvw = (const float*)d_in[2];
  const float* gkw1 = (const float*)d_in[3];
  const float* gkw2 = (const float*)d_in[4];
  const float* gkb2 = (const float*)d_in[5];
  const float* gw   = (const float*)d_in[6];
  const float* gb   = (const float*)d_in[7];
  const float* gnw  = (const float*)d_in[8];
  const float* lnw  = (const float*)d_in[9];
  const float* ow   = (const float*)d_in[10];

  // Workspace layout (bytes), total 232,816,640 (~233 MB):
  //   qkv bf16 [25088,2048]           @ 0          — later reused as y
  //   og  bf16 [2,8,4,3136,256]       @ 102760448  (head doubles as bf16 weight staging)
  //   xs  bf16 [25088,512]            @ 205520896
  //   gklo f32 [25088,16]             @ 231211008
  // g (bf16 [25088,1024]) lives in d_out, consumed before final GEMM.
  if (ws_size < 232816640u) return;
  char* wsb = (char*)d_ws;
  unsigned short* qkv  = (unsigned short*)(wsb + 0);
  unsigned short* og   = (unsigned short*)(wsb + 102760448);
  unsigned short* xs   = (unsigned short*)(wsb + 205520896);
  float*          gklo = (float*)(wsb + 231211008);
  unsigned short* wqb  = og;                         // 2048*512 bf16 (2 MB)
  unsigned short* wgb  = og + 1048576;               // 1024*512 bf16 (1 MB)
  unsigned short* wob  = og;                         // 512*1024 bf16 (1 MB), after k_gate
  unsigned short* y    = qkv;                        // overlay: qkv dead after k_gla2
  unsigned short* g    = (unsigned short*)d_out;     // overlay: consumed by k_gate
  float*          outp = (float*)d_out;

  k_conv_silu<<<NTOK*128/256, 256, 0, stream>>>(x, cw, xs);
  k_w2b<<<1024, 256, 0, stream>>>(qkvw, wqb, 2048*512);
  k_w2b<<<512,  256, 0, stream>>>(gw,   wgb, 1024*512);
  k_gklo<<<NTOK/16, 256, 0, stream>>>(xs, gkw1, gklo);
  k_gemm_mfma<0,1><<<dim3(16,196), 256, 0, stream>>>(xs, wqb, nullptr, qkv, NTOK, 2048, 512);
  k_gemm_mfma<1,1><<<dim3(8,196),  256, 0, stream>>>(xs, wgb, gb,      g,   NTOK, 1024, 512);
  k_gla2<<<256, 256, 0, stream>>>(qkv, gklo, gkw2, gkb2, og);
  k_gate<<<NTOK, 256, 0, stream>>>(og, g, gnw, lnw, y);
  k_w2b<<<512, 256, 0, stream>>>(ow, wob, 512*1024);
  k_gemm_mfma<0,0><<<dim3(4,196), 256, 0, stream>>>(y, wob, nullptr, outp, NTOK, 512, 1024);
}

// Round 6
// 2261.869 us; speedup vs baseline: 5.2222x; 1.1477x over previous
//
#include <hip/hip_runtime.h>
#include <hip/hip_bf16.h>
#include <math.h>

#define NHEADS 4
#define DMODEL 512
#define HQK 128
#define HV 256
#define BBATCH 8
#define SH 56
#define SWW 56
#define SEQN (SH*SWW)          // 3136
#define NTOK (BBATCH*SEQN)     // 25088
#define CH2 32
#define NC2 (SEQN/CH2)         // 98

typedef __bf16 bf16x8 __attribute__((ext_vector_type(8)));
typedef float  f32x4  __attribute__((ext_vector_type(4)));

__device__ __forceinline__ float silu_f(float v){ return v / (1.f + __expf(-v)); }

__device__ __forceinline__ float b2f(unsigned short u){
  union { unsigned int i; float f; } c; c.i = ((unsigned int)u) << 16; return c.f;
}
__device__ __forceinline__ unsigned short f2b(float f){
  union { float fv; unsigned int u; } c; c.fv = f;
  unsigned int r = c.u + 0x7FFFu + ((c.u >> 16) & 1u);   // RNE
  return (unsigned short)(r >> 16);
}
__device__ __forceinline__ float h2f(unsigned short u){
  _Float16 h; __builtin_memcpy(&h, &u, 2); return (float)h;
}
__device__ __forceinline__ unsigned short f2h(float f){
  _Float16 h = (_Float16)f; unsigned short u; __builtin_memcpy(&u, &h, 2); return u;
}
__device__ __forceinline__ float lsig16(float z){          // logsigmoid(z)/16
  float e = __expf(-fabsf(z));
  return (fminf(z, 0.f) - __logf(1.f + e)) * 0.0625f;
}
__device__ __forceinline__ void up8(uint4 v, unsigned short* o){
  o[0]=(unsigned short)v.x; o[1]=(unsigned short)(v.x>>16);
  o[2]=(unsigned short)v.y; o[3]=(unsigned short)(v.y>>16);
  o[4]=(unsigned short)v.z; o[5]=(unsigned short)(v.z>>16);
  o[6]=(unsigned short)v.w; o[7]=(unsigned short)(v.w>>16);
}
__device__ __forceinline__ uint4 pk8(const unsigned short* s){
  uint4 v;
  v.x = (unsigned)s[0] | ((unsigned)s[1]<<16);
  v.y = (unsigned)s[2] | ((unsigned)s[3]<<16);
  v.z = (unsigned)s[4] | ((unsigned)s[5]<<16);
  v.w = (unsigned)s[6] | ((unsigned)s[7]<<16);
  return v;
}

#define GLL16(gp, lp) __builtin_amdgcn_global_load_lds( \
    (const __attribute__((address_space(1))) unsigned int*)(gp), \
    (__attribute__((address_space(3))) unsigned int*)(lp), 16, 0, 0)

// ---------------- fp32 -> bf16 weight conversion ----------------
__global__ __launch_bounds__(256) void k_w2b(const float* __restrict__ w,
                                             unsigned short* __restrict__ o, int n){
  int i = (blockIdx.x*256 + threadIdx.x) << 2;
  if (i >= n) return;
  float4 v = *(const float4*)&w[i];
  ushort4 p;
  p.x = f2b(v.x); p.y = f2b(v.y); p.z = f2b(v.z); p.w = f2b(v.w);
  *(ushort4*)&o[i] = p;
}

// ---------------- Wc = gk_w2[1024,16] @ gk_w1[16,512] -> bf16 [1024][512] ----------------
__global__ __launch_bounds__(256) void k_wc(const float* __restrict__ w1,
                                            const float* __restrict__ w2,
                                            unsigned short* __restrict__ wc){
  int idx = blockIdx.x*256 + threadIdx.x;   // n*512 + k
  int n = idx >> 9, k = idx & 511;
  float acc = 0.f;
  #pragma unroll
  for (int r=0;r<16;++r) acc += w2[n*16+r]*w1[r*512+k];
  wc[idx] = f2b(acc);
}

// ---------------- conv 3x3 depthwise + SiLU -> xs (bf16) ----------------
__global__ __launch_bounds__(256) void k_conv_silu(const float* __restrict__ x,
                                                   const float* __restrict__ cw,
                                                   unsigned short* __restrict__ xs){
  int gid = blockIdx.x*256 + threadIdx.x;     // NTOK*128 threads
  int c4  = (gid & 127) << 2;
  int tok = gid >> 7;
  int b = tok / SEQN, sp = tok % SEQN;
  int hh = sp / SWW, ww = sp % SWW;
  float a0=0.f,a1=0.f,a2=0.f,a3=0.f;
  #pragma unroll
  for (int dh=-1; dh<=1; ++dh){
    int h2 = hh+dh; if (h2<0||h2>=SH) continue;
    #pragma unroll
    for (int dw=-1; dw<=1; ++dw){
      int w2 = ww+dw; if (w2<0||w2>=SWW) continue;
      const float4 xv = *(const float4*)&x[((size_t)(b*SEQN + h2*SWW + w2))*DMODEL + c4];
      int tap = (dh+1)*3 + (dw+1);
      a0 += xv.x * cw[(c4+0)*9 + tap];
      a1 += xv.y * cw[(c4+1)*9 + tap];
      a2 += xv.z * cw[(c4+2)*9 + tap];
      a3 += xv.w * cw[(c4+3)*9 + tap];
    }
  }
  ushort4 o;
  o.x = f2b(silu_f(a0)); o.y = f2b(silu_f(a1)); o.z = f2b(silu_f(a2)); o.w = f2b(silu_f(a3));
  *(ushort4*)&xs[(size_t)tok*DMODEL + c4] = o;
}

// ------- MFMA GEMM: C[M,N] = act(A_bf16[M,K] * W_bf16[N,K]^T + bias) -------
template<int ACT, int CBF>
__global__ __launch_bounds__(256) void k_gemm_mfma(const unsigned short* __restrict__ A,
                                                   const unsigned short* __restrict__ W,
                                                   const float* __restrict__ bias,
                                                   void* __restrict__ Cv,
                                                   int M, int N, int K){
  __shared__ unsigned short sA[128*32];
  __shared__ unsigned short sB[128*32];
  const int tid  = threadIdx.x;
  const int wave = tid >> 6, lane = tid & 63;
  const int lm = lane & 15, quad = lane >> 4;
  const int wm = wave & 1, wn = wave >> 1;
  const int m0 = blockIdx.y * 128, n0 = blockIdx.x * 128;

  const int r0 = tid >> 2,  c0 = (tid & 3) << 3;
  const int f1 = tid + 256;
  const int r1 = f1 >> 2,   c1 = (f1 & 3) << 3;

  f32x4 acc[4][4] = {};

  for (int kt = 0; kt < K; kt += 32){
    GLL16(&A[(size_t)(m0 + r0)*K + kt + c0], &sA[(size_t)tid*8]);
    GLL16(&A[(size_t)(m0 + r1)*K + kt + c1], &sA[(size_t)f1*8]);
    GLL16(&W[(size_t)(n0 + r0)*K + kt + c0], &sB[(size_t)tid*8]);
    GLL16(&W[(size_t)(n0 + r1)*K + kt + c1], &sB[(size_t)f1*8]);
    __syncthreads();
    bf16x8 af[4], bf[4];
    #pragma unroll
    for (int i=0;i<4;++i) af[i] = *(const bf16x8*)&sA[(wm*64 + i*16 + lm)*32 + quad*8];
    #pragma unroll
    for (int j=0;j<4;++j) bf[j] = *(const bf16x8*)&sB[(wn*64 + j*16 + lm)*32 + quad*8];
    #pragma unroll
    for (int i=0;i<4;++i)
      #pragma unroll
      for (int j=0;j<4;++j)
        acc[i][j] = __builtin_amdgcn_mfma_f32_16x16x32_bf16(af[i], bf[j], acc[i][j], 0, 0, 0);
    __syncthreads();
  }

  #pragma unroll
  for (int i=0;i<4;++i){
    #pragma unroll
    for (int r=0;r<4;++r){
      size_t m = (size_t)(m0 + wm*64 + i*16 + quad*4 + r);
      #pragma unroll
      for (int j=0;j<4;++j){
        int n = n0 + wn*64 + j*16 + lm;
        float v = acc[i][j][r];
        if (bias) v += bias[n];
        if (ACT==1) v = silu_f(v);
        if (CBF) ((unsigned short*)Cv)[m*(size_t)N + n] = f2b(v);
        else     ((float*)Cv)[m*(size_t)N + n] = v;
      }
    }
  }
}

// ---------------- prep: gates -> qe_f/ke_f in-place, delta fp16, eb tables ----------------
// grid = 784 blocks (b 0..7 x token-block cB 0..97), 256 threads; thread owns col pair (j, j+1).
__global__ __launch_bounds__(256) void k_prep(unsigned short* __restrict__ qkv,
                                              const unsigned short* __restrict__ z,
                                              unsigned short* __restrict__ dbuf,
                                              unsigned short* __restrict__ ebF,
                                              unsigned short* __restrict__ ebB){
  const int blk = blockIdx.x;
  const int bb = blk / NC2, cB = blk % NC2;
  const int j = threadIdx.x << 1;                 // 0..510
  const size_t base = (size_t)bb*SEQN + cB*CH2;
  const float sc = 0.08838834764831845f;          // 128^-0.5
  float bf0[CH2], bf1[CH2];
  float r0 = 0.f, r1 = 0.f;
  #pragma unroll
  for (int t=0;t<CH2;++t){
    size_t tok = base + t;
    unsigned int zz = *(const unsigned int*)&z[tok*1024 + j];
    r0 += lsig16(b2f((unsigned short)zz));
    r1 += lsig16(b2f((unsigned short)(zz>>16)));
    bf0[t] = r0; bf1[t] = r1;
    unsigned int qq = *(const unsigned int*)&qkv[tok*2048 + j];
    unsigned int kk = *(const unsigned int*)&qkv[tok*2048 + 512 + j];
    float e0 = __expf(r0),  e1 = __expf(r1);
    float n0 = __expf(-r0), n1 = __expf(-r1);
    unsigned int qo = (unsigned)f2b(b2f((unsigned short)qq)*e0*sc)
                    | ((unsigned)f2b(b2f((unsigned short)(qq>>16))*e1*sc) << 16);
    unsigned int ko = (unsigned)f2b(b2f((unsigned short)kk)*n0)
                    | ((unsigned)f2b(b2f((unsigned short)(kk>>16))*n1) << 16);
    *(unsigned int*)&qkv[tok*2048 + j] = qo;
    *(unsigned int*)&qkv[tok*2048 + 512 + j] = ko;
  }
  const int hh = j >> 7, d = j & 127;
  {
    int ef = ((bb*NHEADS + hh)*NC2 + cB)*HQK + d;
    *(unsigned int*)&ebF[ef] = (unsigned)f2h(__expf(bf0[CH2-1]))
                             | ((unsigned)f2h(__expf(bf1[CH2-1])) << 16);
  }
  r0 = 0.f; r1 = 0.f;
  #pragma unroll
  for (int t=CH2-1;t>=0;--t){
    size_t tok = base + t;
    unsigned int zz = *(const unsigned int*)&z[tok*1024 + 512 + j];
    r0 += lsig16(b2f((unsigned short)zz));
    r1 += lsig16(b2f((unsigned short)(zz>>16)));
    float d0 = r0 - bf0[t], d1 = r1 - bf1[t];
    *(unsigned int*)&dbuf[tok*512 + j] = (unsigned)f2h(d0) | ((unsigned)f2h(d1) << 16);
  }
  {
    int eb = ((bb*NHEADS + hh)*NC2 + (NC2-1-cB))*HQK + d;
    *(unsigned int*)&ebB[eb] = (unsigned)f2h(__expf(r0))
                             | ((unsigned)f2h(__expf(r1)) << 16);
  }
}

// ---------------- GLA chunked scan, lean MFMA version, CHUNK=32 ----------------
// grid = 256 blocks: (vq | dir | h | b), 256 threads (4 waves). All gate math precomputed.
__global__ __launch_bounds__(256,1) void k_gla3(const unsigned short* __restrict__ qkvb,
                                                const unsigned short* __restrict__ dbuf,
                                                const unsigned short* __restrict__ ebFt,
                                                const unsigned short* __restrict__ ebBt,
                                                unsigned short* __restrict__ og){
  __shared__ __align__(16) unsigned short sQe[32*136];   // [t][d] stride 136
  __shared__ __align__(16) unsigned short sKe[32*136];   // [t][d]
  __shared__ __align__(16) unsigned short sKeT[128*40];  // [d][t] stride 40
  __shared__ __align__(16) unsigned short sVT[64*40];    // [v][t]
  __shared__ __align__(16) unsigned short sST[64*136];   // [v][d]  (bf16 mirror of S)
  __shared__ __align__(16) unsigned short sP[32*40];     // [t][s]
  __shared__ __align__(16) unsigned short sO[32*72];     // [t][v]
  __shared__ float sEb[128];

  const int tid = threadIdx.x;
  const int bx = blockIdx.x;
  const int vq = bx & 3, dir = (bx>>2)&1, hh = (bx>>3)&3, bb = bx>>5;

  const int w = tid >> 6, lane = tid & 63;
  const int quad = lane >> 4, lm = lane & 15;
  const int mt = w >> 1, nt = w & 1;
  const int ts = tid >> 3, o8 = tid & 7, d16 = o8 << 4;  // qe/ke stage mapping
  const int tl = tid & 31, vg = tid >> 5;                // v stage mapping

  const int qcol = hh*HQK, kcol = 512 + hh*HQK, vcol = 1024 + hh*HV + vq*64;
  const int dcol = hh*HQK;
  const unsigned short* ebT = dir ? ebBt : ebFt;
  const int ebBase = (bb*NHEADS + hh)*NC2*HQK;
  const size_t ogBase = ((size_t)((dir*BBATCH + bb)*NHEADS + hh)) * SEQN * HV;

  f32x4 Sreg[8];
  #pragma unroll
  for (int i=0;i<8;++i){
    #pragma unroll
    for (int r=0;r<4;++r) Sreg[i][r] = 0.f;
  }
  for (int i = tid; i < 64*136; i += 256) sST[i] = 0;
  __syncthreads();

  for (int c = 0; c < NC2; ++c){
    // ---- stage qe/ke (+backward gate fixup), v (transposed), eb ----
    {
      int p = c*CH2 + ts;
      int n = dir ? (SEQN-1-p) : p;
      size_t tok = (size_t)bb*SEQN + n;
      uint4 q0 = *(const uint4*)&qkvb[tok*2048 + qcol + d16];
      uint4 q1 = *(const uint4*)&qkvb[tok*2048 + qcol + d16 + 8];
      uint4 k0 = *(const uint4*)&qkvb[tok*2048 + kcol + d16];
      uint4 k1 = *(const uint4*)&qkvb[tok*2048 + kcol + d16 + 8];
      unsigned short kb[16];
      up8(k0, kb); up8(k1, kb+8);
      if (dir){
        uint4 dd0 = *(const uint4*)&dbuf[tok*512 + dcol + d16];
        uint4 dd1 = *(const uint4*)&dbuf[tok*512 + dcol + d16 + 8];
        unsigned short dh[16], qb[16];
        up8(dd0, dh); up8(dd1, dh+8);
        up8(q0, qb);  up8(q1, qb+8);
        #pragma unroll
        for (int u=0;u<16;++u){
          float du = h2f(dh[u]);
          qb[u] = f2b(b2f(qb[u]) * __expf(du));
          kb[u] = f2b(b2f(kb[u]) * __expf(-du));
        }
        q0 = pk8(qb); q1 = pk8(qb+8);
        k0 = pk8(kb); k1 = pk8(kb+8);
      }
      *(uint4*)&sQe[ts*136 + d16]     = q0;
      *(uint4*)&sQe[ts*136 + d16 + 8] = q1;
      *(uint4*)&sKe[ts*136 + d16]     = k0;
      *(uint4*)&sKe[ts*136 + d16 + 8] = k1;
      #pragma unroll
      for (int u=0;u<16;++u) sKeT[(d16+u)*40 + ts] = kb[u];
    }
    {
      int p = c*CH2 + tl;
      int n = dir ? (SEQN-1-p) : p;
      size_t tok = (size_t)bb*SEQN + n;
      uint4 uv = *(const uint4*)&qkvb[tok*2048 + vcol + vg*8];
      unsigned short su[8];
      up8(uv, su);
      #pragma unroll
      for (int u=0;u<8;++u) sVT[(vg*8+u)*40 + tl] = su[u];
    }
    if (tid < 128) sEb[tid] = h2f(ebT[ebBase + c*HQK + tid]);
    __syncthreads();
    // ---- phase1: A = Qe.Ke^T ; oT += ST.Qe^T ; mask -> sP ----
    bf16x8 qf[2][4];
    #pragma unroll
    for (int tt=0; tt<2; ++tt){
      #pragma unroll
      for (int ks=0; ks<4; ++ks)
        qf[tt][ks] = *(const bf16x8*)&sQe[(tt*16+lm)*136 + ks*32 + quad*8];
    }
    f32x4 a1;
    #pragma unroll
    for (int r=0;r<4;++r) a1[r] = 0.f;
    #pragma unroll
    for (int ks=0; ks<4; ++ks){
      bf16x8 kfr = *(const bf16x8*)&sKe[(nt*16+lm)*136 + ks*32 + quad*8];
      a1 = __builtin_amdgcn_mfma_f32_16x16x32_bf16(qf[mt][ks], kfr, a1, 0, 0, 0);
    }
    f32x4 ot[2];
    #pragma unroll
    for (int tt=0; tt<2; ++tt){
      #pragma unroll
      for (int r=0;r<4;++r) ot[tt][r] = 0.f;
    }
    #pragma unroll
    for (int ks=0; ks<4; ++ks){
      bf16x8 stf = *(const bf16x8*)&sST[(w*16+lm)*136 + ks*32 + quad*8];
      #pragma unroll
      for (int tt=0; tt<2; ++tt)
        ot[tt] = __builtin_amdgcn_mfma_f32_16x16x32_bf16(stf, qf[tt][ks], ot[tt], 0, 0, 0);
    }
    #pragma unroll
    for (int r=0;r<4;++r){
      int t = mt*16 + quad*4 + r, s = nt*16 + lm;
      sP[t*40 + s] = f2b((s <= t) ? a1[r] : 0.f);
    }
    __syncthreads();
    // ---- phase2: S' = eb*(S + VT.KeT^T) ; oT += VT.P^T ----
    bf16x8 vta = *(const bf16x8*)&sVT[(w*16+lm)*40 + quad*8];
    #pragma unroll
    for (int dt=0; dt<8; ++dt){
      bf16x8 kt = *(const bf16x8*)&sKeT[(dt*16+lm)*40 + quad*8];
      Sreg[dt] = __builtin_amdgcn_mfma_f32_16x16x32_bf16(vta, kt, Sreg[dt], 0, 0, 0);
      float eb = sEb[dt*16 + lm];
      #pragma unroll
      for (int r=0;r<4;++r){
        float sv = Sreg[dt][r] * eb;
        Sreg[dt][r] = sv;
        sST[(w*16 + quad*4 + r)*136 + dt*16 + lm] = f2b(sv);
      }
    }
    #pragma unroll
    for (int tt=0; tt<2; ++tt){
      bf16x8 pf = *(const bf16x8*)&sP[(tt*16+lm)*40 + quad*8];
      ot[tt] = __builtin_amdgcn_mfma_f32_16x16x32_bf16(vta, pf, ot[tt], 0, 0, 0);
      #pragma unroll
      for (int r=0;r<4;++r)
        sO[(tt*16+lm)*72 + w*16 + quad*4 + r] = f2b(ot[tt][r]);
    }
    __syncthreads();
    // ---- coalesced o store ----
    {
      int p = c*CH2 + ts;
      int n = dir ? (SEQN-1-p) : p;
      uint4 pk = *(const uint4*)&sO[ts*72 + (o8<<3)];
      *(uint4*)&og[ogBase + (size_t)n*HV + vq*64 + (o8<<3)] = pk;
    }
  } // chunks
}

// ---------------- rmsnorm(f)+rmsnorm(b), gate with silu(g) ----------------
__global__ __launch_bounds__(256) void k_gate(const unsigned short* __restrict__ og,
                                              const unsigned short* __restrict__ g,
                                              const float* __restrict__ gnw,
                                              const float* __restrict__ lnw,
                                              unsigned short* __restrict__ y){
  int tok = blockIdx.x;
  int bb = tok / SEQN, n = tok % SEQN;
  int hh = threadIdx.x >> 6, l = threadIdx.x & 63;
  int j4 = l << 2;
  size_t basef = ((size_t)((0*BBATCH+bb)*NHEADS+hh))*SEQN*HV + (size_t)n*HV + j4;
  size_t baseb = ((size_t)((1*BBATCH+bb)*NHEADS+hh))*SEQN*HV + (size_t)n*HV + j4;
  ushort4 ofu = *(const ushort4*)&og[basef];
  ushort4 obu = *(const ushort4*)&og[baseb];
  float of0=b2f(ofu.x), of1=b2f(ofu.y), of2=b2f(ofu.z), of3=b2f(ofu.w);
  float ob0=b2f(obu.x), ob1=b2f(obu.y), ob2=b2f(obu.z), ob3=b2f(obu.w);
  float ssf = of0*of0 + of1*of1 + of2*of2 + of3*of3;
  float ssb = ob0*ob0 + ob1*ob1 + ob2*ob2 + ob3*ob3;
  #pragma unroll
  for (int m=32;m>=1;m>>=1){ ssf += __shfl_xor(ssf,m,64); ssb += __shfl_xor(ssb,m,64); }
  float rf = rsqrtf(ssf*(1.f/HV) + 1e-5f);
  float rb = rsqrtf(ssb*(1.f/HV) + 1e-5f);
  float4 gn = *(const float4*)&gnw[j4];
  float4 ln = *(const float4*)&lnw[j4];
  ushort4 gvu = *(const ushort4*)&g[(size_t)tok*1024 + hh*HV + j4];  // silu already applied
  float g0=b2f(gvu.x), g1=b2f(gvu.y), g2=b2f(gvu.z), g3=b2f(gvu.w);
  ushort4 out;
  out.x = f2b(g0*(of0*rf*gn.x + ob0*rb*ln.x));
  out.y = f2b(g1*(of1*rf*gn.y + ob1*rb*ln.y));
  out.z = f2b(g2*(of2*rf*gn.z + ob2*rb*ln.z));
  out.w = f2b(g3*(of3*rf*gn.w + ob3*rb*ln.w));
  *(ushort4*)&y[(size_t)tok*1024 + hh*HV + j4] = out;
}

extern "C" void kernel_launch(void* const* d_in, const int* in_sizes, int n_in,
                              void* d_out, int out_size, void* d_ws, size_t ws_size,
                              hipStream_t stream){
  (void)in_sizes; (void)n_in; (void)out_size;
  const float* x    = (const float*)d_in[0];
  const float* cw   = (const float*)d_in[1];
  const float* qkvw = (const float*)d_in[2];
  const float* gkw1 = (const float*)d_in[3];
  const float* gkw2 = (const float*)d_in[4];
  const float* gkb2 = (const float*)d_in[5];
  const float* gw   = (const float*)d_in[6];
  const float* gb   = (const float*)d_in[7];
  const float* gnw  = (const float*)d_in[8];
  const float* lnw  = (const float*)d_in[9];
  const float* ow   = (const float*)d_in[10];

  // Workspace layout (bytes), total 232,816,640 (~233 MB — proven budget):
  //   qkv  bf16 [25088,2048]  @ 0           (103 MB) — prep overwrites q/k with qe_f/ke_f; reused as y
  //   og   bf16 [2,8,4,3136,256] @ 102760448 (103 MB)
  //        pre-scan overlays: xs @ +0 (25.7 MB), zbuf @ +25690112 (51.4 MB),
  //        wqb @ +77070336 (2 MB), wgb @ +79167488 (1 MB), wc @ +80216064 (1 MB);
  //        wob @ +0 after k_gate.
  //   dbuf fp16 [25088,512]   @ 205520896   (25.7 MB)  — delta = b_b - b_f
  //   ebF  fp16 [8,4,98,128]  @ 231211008   (0.8 MB)
  //   ebB  fp16 [8,4,98,128]  @ 232013824   (0.8 MB)
  // g (bf16 [25088,1024]) lives in d_out, consumed before final GEMM.
  if (ws_size < 232816640u) return;
  char* wsb = (char*)d_ws;
  unsigned short* qkv  = (unsigned short*)(wsb + 0);
  unsigned short* og   = (unsigned short*)(wsb + 102760448);
  unsigned short* xs   = og;
  unsigned short* zbuf = (unsigned short*)(wsb + 102760448 + 25690112);
  unsigned short* wqb  = (unsigned short*)(wsb + 102760448 + 77070336);
  unsigned short* wgb  = (unsigned short*)(wsb + 102760448 + 79167488);
  unsigned short* wc   = (unsigned short*)(wsb + 102760448 + 80216064);
  unsigned short* dbuf = (unsigned short*)(wsb + 205520896);
  unsigned short* ebF  = (unsigned short*)(wsb + 231211008);
  unsigned short* ebB  = (unsigned short*)(wsb + 232013824);
  unsigned short* wob  = og;                         // after k_gate, og dead
  unsigned short* y    = qkv;                        // qkv dead after k_gla3
  unsigned short* g    = (unsigned short*)d_out;     // consumed by k_gate
  float*          outp = (float*)d_out;

  k_conv_silu<<<NTOK*128/256, 256, 0, stream>>>(x, cw, xs);
  k_w2b<<<1024, 256, 0, stream>>>(qkvw, wqb, 2048*512);
  k_w2b<<<512,  256, 0, stream>>>(gw,   wgb, 1024*512);
  k_wc<<<2048, 256, 0, stream>>>(gkw1, gkw2, wc);
  k_gemm_mfma<0,1><<<dim3(16,196), 256, 0, stream>>>(xs, wqb, nullptr, qkv,  NTOK, 2048, 512);
  k_gemm_mfma<0,1><<<dim3(8,196),  256, 0, stream>>>(xs, wc,  gkb2,    zbuf, NTOK, 1024, 512);
  k_gemm_mfma<1,1><<<dim3(8,196),  256, 0, stream>>>(xs, wgb, gb,      g,    NTOK, 1024, 512);
  k_prep<<<BBATCH*NC2, 256, 0, stream>>>(qkv, zbuf, dbuf, ebF, ebB);
  k_gla3<<<256, 256, 0, stream>>>(qkv, dbuf, ebF, ebB, og);
  k_gate<<<NTOK, 256, 0, stream>>>(og, g, gnw, lnw, y);
  k_w2b<<<512, 256, 0, stream>>>(ow, wob, 512*1024);
  k_gemm_mfma<0,0><<<dim3(4,196), 256, 0, stream>>>(y, wob, nullptr, outp, NTOK, 512, 1024);
}